// Round 5
// baseline (310.377 us; speedup 1.0000x reference)
//
#include <hip/hip_runtime.h>
#include <stdint.h>

typedef __attribute__((ext_vector_type(4))) float f32x4;
typedef __attribute__((ext_vector_type(8))) short bf16x8;

static __device__ __forceinline__ unsigned short f2bf(float x) {
  unsigned int u = __builtin_bit_cast(unsigned int, x);
  u = (u + 0x7fffu + ((u >> 16) & 1u)) >> 16;
  return (unsigned short)u;
}

#define GLD16(g, l)                                                            \
  __builtin_amdgcn_global_load_lds(                                            \
      (__attribute__((address_space(1))) const void*)(g),                      \
      (__attribute__((address_space(3))) void*)(l), 16, 0, 0)

// ---- pass1: dinv + gb = bf16(dinv[row]*graph); blocks>=4096 convert weights
__global__ __launch_bounds__(256) void rowscale_cvt_k(
    const float* __restrict__ g, float* __restrict__ dinv,
    unsigned short* __restrict__ gb, const float* __restrict__ W1,
    const float* __restrict__ W2, const float* __restrict__ Wout,
    unsigned short* __restrict__ wb) {
  if (blockIdx.x >= 4096) {  // weight conversion: 128 blocks x 2048 elems
    int base = (blockIdx.x - 4096) * 2048;
#pragma unroll
    for (int i = 0; i < 8; ++i) {
      int idx = base + i * 256 + threadIdx.x;
      float v;
      if (idx < 65536) v = W1[idx];
      else if (idx < 131072) v = W2[idx - 65536];
      else v = Wout[idx - 131072];
      wb[idx] = f2bf(v);
    }
    return;
  }
  int row = blockIdx.x * 4 + (threadIdx.x >> 6);
  int lane = threadIdx.x & 63;
  const float* p = g + (long)row * 2048;
  float4 v[8];
  float s = 0.f;
#pragma unroll
  for (int i = 0; i < 8; ++i) {
    v[i] = *(const float4*)(p + (lane + i * 64) * 4);
    s += v[i].x + v[i].y + v[i].z + v[i].w;
  }
#pragma unroll
  for (int off = 32; off; off >>= 1) s += __shfl_xor(s, off, 64);
  float di = rsqrtf(s);
  if (lane == 0) dinv[row] = di;
  unsigned short* q = gb + (long)row * 2048;
#pragma unroll
  for (int i = 0; i < 8; ++i) {
    ushort4 u;
    u.x = f2bf(v[i].x * di); u.y = f2bf(v[i].y * di);
    u.z = f2bf(v[i].z * di); u.w = f2bf(v[i].w * di);
    *(ushort4*)(q + (lane + i * 64) * 4) = u;
  }
}

// ---- node prep: agg[:, :256] = bf16(node); nodeT = (dinv*node)^T -----------
__global__ __launch_bounds__(256) void prep_node_k(
    const float* __restrict__ node, const float* __restrict__ dinv,
    unsigned short* __restrict__ nodeT, unsigned short* __restrict__ agg) {
  __shared__ unsigned short t[64 * 68];
  int tid = threadIdx.x;
  int m0 = blockIdx.x * 64, h0 = blockIdx.y * 64;
  long b = blockIdx.z;
#pragma unroll
  for (int i = 0; i < 4; ++i) {
    int idx = tid + 256 * i;
    int r = idx >> 4, c4 = idx & 15;
    long m = m0 + r;
    float4 v = *(const float4*)(node + (b * 2048 + m) * 256 + h0 + c4 * 4);
    float di = dinv[b * 2048 + m];
    ushort4 u;
    u.x = f2bf(v.x); u.y = f2bf(v.y); u.z = f2bf(v.z); u.w = f2bf(v.w);
    *(ushort4*)(agg + (b * 2048 + m) * 512 + h0 + c4 * 4) = u;
    t[(c4 * 4 + 0) * 68 + r] = f2bf(v.x * di);
    t[(c4 * 4 + 1) * 68 + r] = f2bf(v.y * di);
    t[(c4 * 4 + 2) * 68 + r] = f2bf(v.z * di);
    t[(c4 * 4 + 3) * 68 + r] = f2bf(v.w * di);
  }
  __syncthreads();
#pragma unroll
  for (int i = 0; i < 4; ++i) {
    int idx = tid + 256 * i;
    int hr = idx >> 4, c4 = idx & 15;
    ushort4 o = *(const ushort4*)(&t[hr * 68 + c4 * 4]);
    *(ushort4*)(nodeT + (b * 256 + h0 + hr) * 2048 + m0 + c4 * 4) = o;
  }
}

// ---- MEGA: fused [graph-GEMM K=2048] -> [FC K=256] per 64-row block --------
// 512 thr / 8 waves, wave tile 32x64 over a 64x256 block tile. LDS 80KB:
// stage1: A dbuf 2x8KB @0, B dbuf 2x32KB @16K. stage2: A1 32KB @0, W 32KB @32K.
// TRANS_OUT: MEGA1 (scale dinv, transpose store). else MEGA2 (row-major).
template <bool TRANS_OUT>
__global__ __launch_bounds__(512, 1) void mega_k(
    const unsigned short* __restrict__ A, const unsigned short* __restrict__ Bt,
    const unsigned short* __restrict__ W, const float* __restrict__ bias,
    const float* __restrict__ dinv, unsigned short* __restrict__ Cout,
    long bBatch) {
  __shared__ char lds[81920];
  char* ldsA = lds;            // 2 x 8192
  char* ldsB = lds + 16384;    // 2 x 32768
  char* ldsX = lds;            // stage2: A1 [64][256] bf16 swizzled, 32KB
  char* ldsW = lds + 32768;    // stage2: W chunk [256][64] bf16, 32KB

  int tid = threadIdx.x;
  int lane = tid & 63;
  int w = tid >> 6;            // 0..7
  int wm = w >> 2, wn = w & 3; // wave tile 32x64

  int bid = blockIdx.x;
  int batch = bid & 7;
  int mt = bid >> 3;                       // 0..31 within batch
  long row0 = ((long)batch * 32 + mt) * 64;
  const unsigned short* Bb = Bt + (long)batch * bBatch;

  f32x4 acc[2][4] = {};

  auto stageA = [&](int kt, int buf) {
    int r = tid >> 3, j = tid & 7;
    int jg = j ^ (r & 7);
    GLD16(A + (row0 + r) * 2048 + kt * 64 + jg * 8,
          ldsA + buf * 8192 + w * 1024);
  };
  auto stageB = [&](int kt, int buf) {
#pragma unroll
    for (int i = 0; i < 4; ++i) {
      int slot = i * 512 + tid;
      int c = slot >> 3, j = slot & 7;
      int jg = j ^ (c & 7);
      GLD16(Bb + (long)c * 2048 + kt * 64 + jg * 8,
            ldsB + buf * 32768 + (i * 8 + w) * 1024);
    }
  };
  auto compute1 = [&](int buf) {
    char* bA = ldsA + buf * 8192;
    char* bB = ldsB + buf * 32768;
    bf16x8 a[2][2], bb[4][2];
#pragma unroll
    for (int m = 0; m < 2; ++m)
#pragma unroll
      for (int kk = 0; kk < 2; ++kk) {
        int row = wm * 32 + m * 16 + (lane & 15);
        int off = (row * 128 + kk * 64 + (lane >> 4) * 16) ^ ((row & 7) << 4);
        a[m][kk] = *(const bf16x8*)(bA + off);
      }
#pragma unroll
    for (int n = 0; n < 4; ++n)
#pragma unroll
      for (int kk = 0; kk < 2; ++kk) {
        int col = wn * 64 + n * 16 + (lane & 15);
        int off = (col * 128 + kk * 64 + (lane >> 4) * 16) ^ ((col & 7) << 4);
        bb[n][kk] = *(const bf16x8*)(bB + off);
      }
#pragma unroll
    for (int m = 0; m < 2; ++m)
#pragma unroll
      for (int n = 0; n < 4; ++n) {
        acc[m][n] = __builtin_amdgcn_mfma_f32_16x16x32_bf16(a[m][0], bb[n][0],
                                                            acc[m][n], 0, 0, 0);
        acc[m][n] = __builtin_amdgcn_mfma_f32_16x16x32_bf16(a[m][1], bb[n][1],
                                                            acc[m][n], 0, 0, 0);
      }
  };

  // ---- stage 1: acc = A[64 rows, 2048] @ Bb[256, 2048]^T ----
  stageA(0, 0);
  stageB(0, 0);
  __syncthreads();
  int cur = 0;
  for (int t = 0; t < 32; ++t) {
    int nxt = cur ^ 1;
    if (t + 1 < 32) {
      stageA(t + 1, nxt);
      stageB(t + 1, nxt);
    }
    compute1(cur);
    __syncthreads();
    cur = nxt;
  }
  __syncthreads();  // all compute done before overwriting stage-1 LDS

  // ---- transition: A1 (raw acc) -> ldsX as bf16, MFMA-A layout, swizzled ----
#pragma unroll
  for (int m = 0; m < 2; ++m)
#pragma unroll
    for (int n = 0; n < 4; ++n) {
      int col = wn * 64 + n * 16 + (lane & 15);
#pragma unroll
      for (int r = 0; r < 4; ++r) {
        int row = wm * 32 + m * 16 + (lane >> 4) * 4 + r;
        int off = (row * 512 + col * 2) ^ ((row & 7) << 4);
        *(unsigned short*)(ldsX + off) = f2bf(acc[m][n][r]);
      }
    }

  // ---- stage 2: acc2 = relu(A1 @ W^T + b); K=256, W single-buffered ----
  f32x4 acc2[2][4] = {};
  for (int kt = 0; kt < 4; ++kt) {
    __syncthreads();  // protect ldsW (and ldsX writes on first iter)
#pragma unroll
    for (int i = 0; i < 4; ++i) {
      int slot = i * 512 + tid;
      int c = slot >> 3, j = slot & 7;
      int jg = j ^ (c & 7);
      GLD16(W + (long)c * 256 + kt * 64 + jg * 8, ldsW + (i * 8 + w) * 1024);
    }
    __syncthreads();  // GLD complete
    bf16x8 a[2][2], bb[4][2];
#pragma unroll
    for (int m = 0; m < 2; ++m)
#pragma unroll
      for (int kk = 0; kk < 2; ++kk) {
        int row = wm * 32 + m * 16 + (lane & 15);
        int off = (row * 512 + kt * 128 + kk * 64 + (lane >> 4) * 16) ^
                  ((row & 7) << 4);
        a[m][kk] = *(const bf16x8*)(ldsX + off);
      }
#pragma unroll
    for (int n = 0; n < 4; ++n)
#pragma unroll
      for (int kk = 0; kk < 2; ++kk) {
        int col = wn * 64 + n * 16 + (lane & 15);
        int off = (col * 128 + kk * 64 + (lane >> 4) * 16) ^ ((col & 7) << 4);
        bb[n][kk] = *(const bf16x8*)(ldsW + off);
      }
#pragma unroll
    for (int m = 0; m < 2; ++m)
#pragma unroll
      for (int n = 0; n < 4; ++n) {
        acc2[m][n] = __builtin_amdgcn_mfma_f32_16x16x32_bf16(a[m][0], bb[n][0],
                                                             acc2[m][n], 0, 0, 0);
        acc2[m][n] = __builtin_amdgcn_mfma_f32_16x16x32_bf16(a[m][1], bb[n][1],
                                                             acc2[m][n], 0, 0, 0);
      }
  }

  // ---- epilogue ----
  if (TRANS_OUT) {
    __syncthreads();
    unsigned short* tb = (unsigned short*)lds;  // [256][72] pad, 36KB
#pragma unroll
    for (int m = 0; m < 2; ++m)
#pragma unroll
      for (int n = 0; n < 4; ++n) {
        int col = wn * 64 + n * 16 + (lane & 15);
        float bv = bias[col];
#pragma unroll
        for (int r = 0; r < 4; ++r) {
          int rl = wm * 32 + m * 16 + (lane >> 4) * 4 + r;
          float v = fmaxf(acc2[m][n][r] + bv, 0.f) * dinv[row0 + rl];
          tb[col * 72 + rl] = f2bf(v);
        }
      }
    __syncthreads();
    int rin = (int)(row0 & 2047);
#pragma unroll
    for (int i = 0; i < 4; ++i) {
      int id = i * 512 + tid;  // 2048 chunks of 8 bf16
      int col = id >> 3, seg = id & 7;
      bf16x8 u = *(const bf16x8*)(tb + col * 72 + seg * 8);
      *(bf16x8*)(Cout + ((long)batch * 256 + col) * 2048 + rin + seg * 8) = u;
    }
  } else {
#pragma unroll
    for (int m = 0; m < 2; ++m)
#pragma unroll
      for (int n = 0; n < 4; ++n) {
        int col = wn * 64 + n * 16 + (lane & 15);
        float bv = bias[col];
#pragma unroll
        for (int r = 0; r < 4; ++r) {
          long row = row0 + wm * 32 + m * 16 + (lane >> 4) * 4 + r;
          float v = fmaxf(acc2[m][n][r] + bv, 0.f);
          Cout[row * 512 + col] = f2bf(v);
        }
      }
  }
}

// ---- F3 GEMM: C[128,128] = A[128,512] @ Bt[128,512]^T + bias, relu, f32 ----
__global__ __launch_bounds__(256, 2) void gemm_f3(
    const unsigned short* __restrict__ A, const unsigned short* __restrict__ Bt,
    const float* __restrict__ bias, float* __restrict__ C) {
  __shared__ char lds[65536];
  char* ldsA = lds;
  char* ldsB = lds + 32768;
  int tid = threadIdx.x;
  int lane = tid & 63;
  int w = tid >> 6;
  int wm = w >> 1, wn = w & 1;

  int bid = blockIdx.x;
  int gt = ((bid & 7) << 5) + (bid >> 3);
  int mt = gt >> 1;
  int col0 = (gt & 1) * 128;
  long row0 = (long)mt * 128;

  f32x4 acc[4][4] = {};
  auto stageA = [&](int kt, int buf) {
#pragma unroll
    for (int i = 0; i < 4; ++i) {
      int slot = i * 256 + tid;
      int r = slot >> 3, j = slot & 7;
      int jg = j ^ (r & 7);
      GLD16(A + (row0 + r) * 512 + kt * 64 + jg * 8,
            ldsA + buf * 16384 + (i * 4 + w) * 1024);
    }
  };
  auto stageB = [&](int kt, int buf) {
#pragma unroll
    for (int i = 0; i < 4; ++i) {
      int slot = i * 256 + tid;
      int c = slot >> 3, j = slot & 7;
      int jg = j ^ (c & 7);
      GLD16(Bt + (long)(col0 + c) * 512 + kt * 64 + jg * 8,
            ldsB + buf * 16384 + (i * 4 + w) * 1024);
    }
  };
  auto compute = [&](int buf) {
    char* bA = ldsA + buf * 16384;
    char* bB = ldsB + buf * 16384;
    bf16x8 a[4][2], bb[4][2];
#pragma unroll
    for (int m = 0; m < 4; ++m)
#pragma unroll
      for (int kk = 0; kk < 2; ++kk) {
        int row = wm * 64 + m * 16 + (lane & 15);
        int off = (row * 128 + kk * 64 + (lane >> 4) * 16) ^ ((row & 7) << 4);
        a[m][kk] = *(const bf16x8*)(bA + off);
      }
#pragma unroll
    for (int n = 0; n < 4; ++n)
#pragma unroll
      for (int kk = 0; kk < 2; ++kk) {
        int col = wn * 64 + n * 16 + (lane & 15);
        int off = (col * 128 + kk * 64 + (lane >> 4) * 16) ^ ((col & 7) << 4);
        bb[n][kk] = *(const bf16x8*)(bB + off);
      }
#pragma unroll
    for (int m = 0; m < 4; ++m)
#pragma unroll
      for (int n = 0; n < 4; ++n) {
        acc[m][n] = __builtin_amdgcn_mfma_f32_16x16x32_bf16(a[m][0], bb[n][0],
                                                            acc[m][n], 0, 0, 0);
        acc[m][n] = __builtin_amdgcn_mfma_f32_16x16x32_bf16(a[m][1], bb[n][1],
                                                            acc[m][n], 0, 0, 0);
      }
  };

  stageA(0, 0);
  stageB(0, 0);
  __syncthreads();
  int cur = 0;
  for (int t = 0; t < 8; ++t) {
    int nxt = cur ^ 1;
    if (t + 1 < 8) {
      stageA(t + 1, nxt);
      stageB(t + 1, nxt);
    }
    compute(cur);
    __syncthreads();
    cur = nxt;
  }
#pragma unroll
  for (int m = 0; m < 4; ++m)
#pragma unroll
    for (int n = 0; n < 4; ++n) {
      int col = col0 + wn * 64 + n * 16 + (lane & 15);
      float bv = bias[col & 255];
#pragma unroll
      for (int r = 0; r < 4; ++r) {
        long row = row0 + wm * 64 + m * 16 + (lane >> 4) * 4 + r;
        C[row * 256 + (col & 255)] = fmaxf(acc[m][n][r] + bv, 0.f);
      }
    }
}

extern "C" void kernel_launch(void* const* d_in, const int* in_sizes, int n_in,
                              void* d_out, int out_size, void* d_ws,
                              size_t ws_size, hipStream_t stream) {
  const float* node = (const float*)d_in[0];   // [8,2048,256]
  const float* graph = (const float*)d_in[1];  // [8,2048,2048]
  const float* W1 = (const float*)d_in[2];
  const float* b1 = (const float*)d_in[3];
  const float* W2 = (const float*)d_in[4];
  const float* b2 = (const float*)d_in[5];
  const float* Wout = (const float*)d_in[6];   // [256,512]
  const float* bout = (const float*)d_in[7];
  float* out = (float*)d_out;

  char* p = (char*)d_ws;
  float* dinv = (float*)p;                    p += 16384 * 4;
  unsigned short* wb = (unsigned short*)p;    p += 262144 * 2;
  unsigned short* gb = (unsigned short*)p;    p += 8L * 2048 * 2048 * 2;  // 64MB
  unsigned short* nodeT = (unsigned short*)p; p += 8L * 256 * 2048 * 2;
  unsigned short* xT = (unsigned short*)p;    p += 8L * 256 * 2048 * 2;
  unsigned short* agg = (unsigned short*)p;   p += 8L * 2048 * 512 * 2;

  // 1. dinv + scaled bf16 graph + weight conversion (one launch)
  rowscale_cvt_k<<<4224, 256, 0, stream>>>(graph, dinv, gb, W1, W2, Wout, wb);
  // 2. node prep
  prep_node_k<<<dim3(32, 4, 8), 256, 0, stream>>>(node, dinv, nodeT, agg);
  // 3. MEGA1: X1s^T = (dinv .* relu((gb @ nodeT^T) @ W1^T + b1))^T -> xT
  mega_k<true><<<256, 512, 0, stream>>>(gb, nodeT, wb, b1, dinv, xT,
                                        256L * 2048);
  // 4. MEGA2: X2 = relu((gb @ xT^T) @ W2^T + b2) -> agg[:, 256:512]
  mega_k<false><<<256, 512, 0, stream>>>(gb, xT, wb + 65536, b2, dinv,
                                         agg + 256, 256L * 2048);
  // 5. F3: out = relu(agg @ Wout^T + bout)
  gemm_f3<<<256, 256, 0, stream>>>(agg, wb + 131072, bout, out);
}

// Round 6
// 296.500 us; speedup vs baseline: 1.0468x; 1.0468x over previous
//
#include <hip/hip_runtime.h>
#include <stdint.h>

typedef __attribute__((ext_vector_type(4))) float f32x4;
typedef __attribute__((ext_vector_type(8))) short bf16x8;

static __device__ __forceinline__ unsigned short f2bf(float x) {
  unsigned int u = __builtin_bit_cast(unsigned int, x);
  u = (u + 0x7fffu + ((u >> 16) & 1u)) >> 16;
  return (unsigned short)u;
}

#define GLD16(g, l)                                                            \
  __builtin_amdgcn_global_load_lds(                                            \
      (__attribute__((address_space(1))) const void*)(g),                      \
      (__attribute__((address_space(3))) void*)(l), 16, 0, 0)

// ---- pass1: dinv + gb = bf16(dinv[row]*graph); blocks>=4096 convert weights
__global__ __launch_bounds__(256) void rowscale_cvt_k(
    const float* __restrict__ g, float* __restrict__ dinv,
    unsigned short* __restrict__ gb, const float* __restrict__ W1,
    const float* __restrict__ W2, const float* __restrict__ Wout,
    unsigned short* __restrict__ wb) {
  if (blockIdx.x >= 4096) {  // weight conversion: 128 blocks x 2048 elems
    int base = (blockIdx.x - 4096) * 2048;
#pragma unroll
    for (int i = 0; i < 8; ++i) {
      int idx = base + i * 256 + threadIdx.x;
      float v;
      if (idx < 65536) v = W1[idx];
      else if (idx < 131072) v = W2[idx - 65536];
      else v = Wout[idx - 131072];
      wb[idx] = f2bf(v);
    }
    return;
  }
  int row = blockIdx.x * 4 + (threadIdx.x >> 6);
  int lane = threadIdx.x & 63;
  const float* p = g + (long)row * 2048;
  float4 v[8];
  float s = 0.f;
#pragma unroll
  for (int i = 0; i < 8; ++i) {
    v[i] = *(const float4*)(p + (lane + i * 64) * 4);
    s += v[i].x + v[i].y + v[i].z + v[i].w;
  }
#pragma unroll
  for (int off = 32; off; off >>= 1) s += __shfl_xor(s, off, 64);
  float di = rsqrtf(s);
  if (lane == 0) dinv[row] = di;
  unsigned short* q = gb + (long)row * 2048;
#pragma unroll
  for (int i = 0; i < 8; ++i) {
    ushort4 u;
    u.x = f2bf(v[i].x * di); u.y = f2bf(v[i].y * di);
    u.z = f2bf(v[i].z * di); u.w = f2bf(v[i].w * di);
    *(ushort4*)(q + (lane + i * 64) * 4) = u;
  }
}

// ---- node prep: nodeB = bf16(node) dense; nodeT = (dinv*node)^T ------------
__global__ __launch_bounds__(256) void prep_node_k(
    const float* __restrict__ node, const float* __restrict__ dinv,
    unsigned short* __restrict__ nodeT, unsigned short* __restrict__ nodeB) {
  __shared__ unsigned short t[64 * 68];
  int tid = threadIdx.x;
  int m0 = blockIdx.x * 64, h0 = blockIdx.y * 64;
  long b = blockIdx.z;
#pragma unroll
  for (int i = 0; i < 4; ++i) {
    int idx = tid + 256 * i;
    int r = idx >> 4, c4 = idx & 15;
    long m = m0 + r;
    float4 v = *(const float4*)(node + (b * 2048 + m) * 256 + h0 + c4 * 4);
    float di = dinv[b * 2048 + m];
    ushort4 u;
    u.x = f2bf(v.x); u.y = f2bf(v.y); u.z = f2bf(v.z); u.w = f2bf(v.w);
    *(ushort4*)(nodeB + (b * 2048 + m) * 256 + h0 + c4 * 4) = u;
    t[(c4 * 4 + 0) * 68 + r] = f2bf(v.x * di);
    t[(c4 * 4 + 1) * 68 + r] = f2bf(v.y * di);
    t[(c4 * 4 + 2) * 68 + r] = f2bf(v.z * di);
    t[(c4 * 4 + 3) * 68 + r] = f2bf(v.w * di);
  }
  __syncthreads();
#pragma unroll
  for (int i = 0; i < 4; ++i) {
    int idx = tid + 256 * i;
    int hr = idx >> 4, c4 = idx & 15;
    ushort4 o = *(const ushort4*)(&t[hr * 68 + c4 * 4]);
    *(ushort4*)(nodeT + (b * 256 + h0 + hr) * 2048 + m0 + c4 * 4) = o;
  }
}

// ============ shared pieces for the MEGA kernels ============================
// stage1 ring-3: A 3x8KB @0, B 3x32KB @24576 (total 122880 LDS).
// Each thread issues exactly 5 GLD16 per stage (A:1, B:4) -> vmcnt units.
#define LDS_BYTES 122880
#define B_RING 24576

// ---- MEGA1: X1s^T = (dinv .* relu((gb @ nodeT^T) @ W1^T + b1))^T -----------
__global__ __launch_bounds__(512, 1) void mega1_k(
    const unsigned short* __restrict__ A, const unsigned short* __restrict__ Bt,
    const unsigned short* __restrict__ W, const float* __restrict__ bias,
    const float* __restrict__ dinv, unsigned short* __restrict__ Cout) {
  __shared__ char lds[LDS_BYTES];
  int tid = threadIdx.x;
  int lane = tid & 63;
  int w = tid >> 6;
  int wm = w >> 2, wn = w & 3;  // wave tile 32x64 over 64x256 block tile

  int bid = blockIdx.x;
  int batch = bid & 7;
  int mt = bid >> 3;
  long row0 = ((long)batch * 32 + mt) * 64;
  const unsigned short* Bb = Bt + (long)batch * (256L * 2048);

  f32x4 acc[2][4] = {};

  auto stageA = [&](int kt, int buf) {
    int r = tid >> 3, j = tid & 7;
    int jg = j ^ (r & 7);
    GLD16(A + (row0 + r) * 2048 + kt * 64 + jg * 8, lds + buf * 8192 + w * 1024);
  };
  auto stageB = [&](int kt, int buf) {
#pragma unroll
    for (int i = 0; i < 4; ++i) {
      int slot = i * 512 + tid;
      int c = slot >> 3, j = slot & 7;
      int jg = j ^ (c & 7);
      GLD16(Bb + (long)c * 2048 + kt * 64 + jg * 8,
            lds + B_RING + buf * 32768 + (i * 8 + w) * 1024);
    }
  };
  auto compute1 = [&](int buf) {
    char* bA = lds + buf * 8192;
    char* bB = lds + B_RING + buf * 32768;
    bf16x8 a[2][2], bb[4][2];
#pragma unroll
    for (int m = 0; m < 2; ++m)
#pragma unroll
      for (int kk = 0; kk < 2; ++kk) {
        int row = wm * 32 + m * 16 + (lane & 15);
        int off = (row * 128 + kk * 64 + (lane >> 4) * 16) ^ ((row & 7) << 4);
        a[m][kk] = *(const bf16x8*)(bA + off);
      }
#pragma unroll
    for (int n = 0; n < 4; ++n)
#pragma unroll
      for (int kk = 0; kk < 2; ++kk) {
        int col = wn * 64 + n * 16 + (lane & 15);
        int off = (col * 128 + kk * 64 + (lane >> 4) * 16) ^ ((col & 7) << 4);
        bb[n][kk] = *(const bf16x8*)(bB + off);
      }
#pragma unroll
    for (int m = 0; m < 2; ++m)
#pragma unroll
      for (int n = 0; n < 4; ++n) {
        acc[m][n] = __builtin_amdgcn_mfma_f32_16x16x32_bf16(a[m][0], bb[n][0],
                                                            acc[m][n], 0, 0, 0);
        acc[m][n] = __builtin_amdgcn_mfma_f32_16x16x32_bf16(a[m][1], bb[n][1],
                                                            acc[m][n], 0, 0, 0);
      }
  };

  // stage 1: ring-3, counted vmcnt (T4): loads stay 2 tiles in flight.
  stageA(0, 0); stageB(0, 0);
  stageA(1, 1); stageB(1, 1);
  for (int t = 0; t < 32; ++t) {
    if (t < 31) asm volatile("s_waitcnt vmcnt(5)" ::: "memory");
    else        asm volatile("s_waitcnt vmcnt(0)" ::: "memory");
    __builtin_amdgcn_s_barrier();
    if (t + 2 < 32) {
      int nb = (t + 2) % 3;
      stageA(t + 2, nb);
      stageB(t + 2, nb);
    }
    compute1(t % 3);
  }
  asm volatile("s_waitcnt vmcnt(0)" ::: "memory");
  __syncthreads();

  // transition: A1 -> ldsX @0, [64][256] bf16, row-stride 512B, swizzled
  char* ldsX = lds;
  char* ldsW = lds + 32768;
#pragma unroll
  for (int m = 0; m < 2; ++m)
#pragma unroll
    for (int n = 0; n < 4; ++n) {
      int col = wn * 64 + n * 16 + (lane & 15);
#pragma unroll
      for (int r = 0; r < 4; ++r) {
        int row = wm * 32 + m * 16 + (lane >> 4) * 4 + r;
        int off = (row * 512 + col * 2) ^ ((row & 7) << 4);
        *(unsigned short*)(ldsX + off) = f2bf(acc[m][n][r]);
      }
    }

  // stage 2: acc2 = A1 @ W1^T, K=256
  f32x4 acc2[2][4] = {};
  for (int kt = 0; kt < 4; ++kt) {
    __syncthreads();
#pragma unroll
    for (int i = 0; i < 4; ++i) {
      int slot = i * 512 + tid;
      int c = slot >> 3, j = slot & 7;
      int jg = j ^ (c & 7);
      GLD16(W + (long)c * 256 + kt * 64 + jg * 8, ldsW + (i * 8 + w) * 1024);
    }
    __syncthreads();
    bf16x8 a[2][2], bb[4][2];
#pragma unroll
    for (int m = 0; m < 2; ++m)
#pragma unroll
      for (int kk = 0; kk < 2; ++kk) {
        int row = wm * 32 + m * 16 + (lane & 15);
        int off = (row * 512 + kt * 128 + kk * 64 + (lane >> 4) * 16) ^
                  ((row & 7) << 4);
        a[m][kk] = *(const bf16x8*)(ldsX + off);
      }
#pragma unroll
    for (int n = 0; n < 4; ++n)
#pragma unroll
      for (int kk = 0; kk < 2; ++kk) {
        int col = wn * 64 + n * 16 + (lane & 15);
        int off = (col * 128 + kk * 64 + (lane >> 4) * 16) ^ ((col & 7) << 4);
        bb[n][kk] = *(const bf16x8*)(ldsW + off);
      }
#pragma unroll
    for (int m = 0; m < 2; ++m)
#pragma unroll
      for (int n = 0; n < 4; ++n) {
        acc2[m][n] = __builtin_amdgcn_mfma_f32_16x16x32_bf16(a[m][0], bb[n][0],
                                                             acc2[m][n], 0, 0, 0);
        acc2[m][n] = __builtin_amdgcn_mfma_f32_16x16x32_bf16(a[m][1], bb[n][1],
                                                             acc2[m][n], 0, 0, 0);
      }
  }

  // epilogue: X1s^T (transpose store via padded LDS)
  __syncthreads();
  unsigned short* tb = (unsigned short*)lds;  // [256][72]
#pragma unroll
  for (int m = 0; m < 2; ++m)
#pragma unroll
    for (int n = 0; n < 4; ++n) {
      int col = wn * 64 + n * 16 + (lane & 15);
      float bv = bias[col];
#pragma unroll
      for (int r = 0; r < 4; ++r) {
        int rl = wm * 32 + m * 16 + (lane >> 4) * 4 + r;
        float v = fmaxf(acc2[m][n][r] + bv, 0.f) * dinv[row0 + rl];
        tb[col * 72 + rl] = f2bf(v);
      }
    }
  __syncthreads();
  int rin = (int)(row0 & 2047);
#pragma unroll
  for (int i = 0; i < 4; ++i) {
    int id = i * 512 + tid;
    int col = id >> 3, seg = id & 7;
    bf16x8 u = *(const bf16x8*)(tb + col * 72 + seg * 8);
    *(bf16x8*)(Cout + ((long)batch * 256 + col) * 2048 + rin + seg * 8) = u;
  }
}

// ---- MEGA2F3: out = relu([node | relu((gb@X1s^T)@W2^T+b2)] @ Wout^T + bout)
__global__ __launch_bounds__(512, 1) void mega2f3_k(
    const unsigned short* __restrict__ A, const unsigned short* __restrict__ Bt,
    const unsigned short* __restrict__ W2b, const float* __restrict__ b2,
    const unsigned short* __restrict__ nodeB, const unsigned short* __restrict__ Wo,
    const float* __restrict__ bout, float* __restrict__ out) {
  __shared__ char lds[LDS_BYTES];
  int tid = threadIdx.x;
  int lane = tid & 63;
  int w = tid >> 6;
  int wm = w >> 2, wn = w & 3;

  int bid = blockIdx.x;
  int batch = bid & 7;
  int mt = bid >> 3;
  long row0 = ((long)batch * 32 + mt) * 64;
  const unsigned short* Bb = Bt + (long)batch * (256L * 2048);

  f32x4 acc[2][4] = {};

  auto stageA = [&](int kt, int buf) {
    int r = tid >> 3, j = tid & 7;
    int jg = j ^ (r & 7);
    GLD16(A + (row0 + r) * 2048 + kt * 64 + jg * 8, lds + buf * 8192 + w * 1024);
  };
  auto stageB = [&](int kt, int buf) {
#pragma unroll
    for (int i = 0; i < 4; ++i) {
      int slot = i * 512 + tid;
      int c = slot >> 3, j = slot & 7;
      int jg = j ^ (c & 7);
      GLD16(Bb + (long)c * 2048 + kt * 64 + jg * 8,
            lds + B_RING + buf * 32768 + (i * 8 + w) * 1024);
    }
  };
  auto compute1 = [&](int buf) {
    char* bA = lds + buf * 8192;
    char* bB = lds + B_RING + buf * 32768;
    bf16x8 a[2][2], bb[4][2];
#pragma unroll
    for (int m = 0; m < 2; ++m)
#pragma unroll
      for (int kk = 0; kk < 2; ++kk) {
        int row = wm * 32 + m * 16 + (lane & 15);
        int off = (row * 128 + kk * 64 + (lane >> 4) * 16) ^ ((row & 7) << 4);
        a[m][kk] = *(const bf16x8*)(bA + off);
      }
#pragma unroll
    for (int n = 0; n < 4; ++n)
#pragma unroll
      for (int kk = 0; kk < 2; ++kk) {
        int col = wn * 64 + n * 16 + (lane & 15);
        int off = (col * 128 + kk * 64 + (lane >> 4) * 16) ^ ((col & 7) << 4);
        bb[n][kk] = *(const bf16x8*)(bB + off);
      }
#pragma unroll
    for (int m = 0; m < 2; ++m)
#pragma unroll
      for (int n = 0; n < 4; ++n) {
        acc[m][n] = __builtin_amdgcn_mfma_f32_16x16x32_bf16(a[m][0], bb[n][0],
                                                            acc[m][n], 0, 0, 0);
        acc[m][n] = __builtin_amdgcn_mfma_f32_16x16x32_bf16(a[m][1], bb[n][1],
                                                            acc[m][n], 0, 0, 0);
      }
  };

  // stage 1: A2 = gb @ X1s^T (ring-3, counted vmcnt)
  stageA(0, 0); stageB(0, 0);
  stageA(1, 1); stageB(1, 1);
  for (int t = 0; t < 32; ++t) {
    if (t < 31) asm volatile("s_waitcnt vmcnt(5)" ::: "memory");
    else        asm volatile("s_waitcnt vmcnt(0)" ::: "memory");
    __builtin_amdgcn_s_barrier();
    if (t + 2 < 32) {
      int nb = (t + 2) % 3;
      stageA(t + 2, nb);
      stageB(t + 2, nb);
    }
    compute1(t % 3);
  }
  asm volatile("s_waitcnt vmcnt(0)" ::: "memory");
  __syncthreads();

  // transition: A2 -> ldsX @0 ([64][256] bf16, swizzled)
  char* ldsX = lds;
  char* ldsW = lds + 32768;
#pragma unroll
  for (int m = 0; m < 2; ++m)
#pragma unroll
    for (int n = 0; n < 4; ++n) {
      int col = wn * 64 + n * 16 + (lane & 15);
#pragma unroll
      for (int r = 0; r < 4; ++r) {
        int row = wm * 32 + m * 16 + (lane >> 4) * 4 + r;
        int off = (row * 512 + col * 2) ^ ((row & 7) << 4);
        *(unsigned short*)(ldsX + off) = f2bf(acc[m][n][r]);
      }
    }

  // stage 2: acc2 = A2 @ W2^T, K=256
  f32x4 acc2[2][4] = {};
  for (int kt = 0; kt < 4; ++kt) {
    __syncthreads();
#pragma unroll
    for (int i = 0; i < 4; ++i) {
      int slot = i * 512 + tid;
      int c = slot >> 3, j = slot & 7;
      int jg = j ^ (c & 7);
      GLD16(W2b + (long)c * 256 + kt * 64 + jg * 8, ldsW + (i * 8 + w) * 1024);
    }
    __syncthreads();
    bf16x8 a[2][2], bb[4][2];
#pragma unroll
    for (int m = 0; m < 2; ++m)
#pragma unroll
      for (int kk = 0; kk < 2; ++kk) {
        int row = wm * 32 + m * 16 + (lane & 15);
        int off = (row * 512 + kt * 128 + kk * 64 + (lane >> 4) * 16) ^
                  ((row & 7) << 4);
        a[m][kk] = *(const bf16x8*)(ldsX + off);
      }
#pragma unroll
    for (int n = 0; n < 4; ++n)
#pragma unroll
      for (int kk = 0; kk < 2; ++kk) {
        int col = wn * 64 + n * 16 + (lane & 15);
        int off = (col * 128 + kk * 64 + (lane >> 4) * 16) ^ ((col & 7) << 4);
        bb[n][kk] = *(const bf16x8*)(ldsW + off);
      }
#pragma unroll
    for (int m = 0; m < 2; ++m)
#pragma unroll
      for (int n = 0; n < 4; ++n) {
        acc2[m][n] = __builtin_amdgcn_mfma_f32_16x16x32_bf16(a[m][0], bb[n][0],
                                                             acc2[m][n], 0, 0, 0);
        acc2[m][n] = __builtin_amdgcn_mfma_f32_16x16x32_bf16(a[m][1], bb[n][1],
                                                             acc2[m][n], 0, 0, 0);
      }
  }
  __syncthreads();  // stage-2 reads done before overwriting ldsX/ldsW

  // transition 2: X2 = relu(acc2 + b2) -> A_hi @32768; nodeB tile -> A_lo @0
  char* Alo = lds;            // [64][256] bf16 swizzled (node half)
  char* Ahi = lds + 32768;    // [64][256] bf16 swizzled (X2 half)
  char* ldsW3 = lds + 65536;  // [256][64] W-out chunk
#pragma unroll
  for (int m = 0; m < 2; ++m)
#pragma unroll
    for (int n = 0; n < 4; ++n) {
      int col = wn * 64 + n * 16 + (lane & 15);
      float bv = b2[col];
#pragma unroll
      for (int r = 0; r < 4; ++r) {
        int row = wm * 32 + m * 16 + (lane >> 4) * 4 + r;
        int off = (row * 512 + col * 2) ^ ((row & 7) << 4);
        *(unsigned short*)(Ahi + off) = f2bf(fmaxf(acc2[m][n][r] + bv, 0.f));
      }
    }
#pragma unroll
  for (int i = 0; i < 4; ++i) {  // nodeB -> A_lo (32KB, 4 GLD16/thread)
    int slot = i * 512 + tid;
    int r = slot >> 5, j = slot & 31;
    int jg = j ^ (r & 7);
    GLD16(nodeB + (row0 + r) * 256 + jg * 8, Alo + (i * 8 + w) * 1024);
  }

  // stage 3: acc3 = [node|X2] @ Wout^T, K=512 (8 chunks of 64)
  f32x4 acc3[2][4] = {};
  for (int kt = 0; kt < 8; ++kt) {
    __syncthreads();  // first iter: also covers Ahi ds_writes + Alo GLDs
#pragma unroll
    for (int i = 0; i < 4; ++i) {
      int slot = i * 512 + tid;
      int c = slot >> 3, j = slot & 7;
      int jg = j ^ (c & 7);
      GLD16(Wo + (long)c * 512 + kt * 64 + jg * 8, ldsW3 + (i * 8 + w) * 1024);
    }
    __syncthreads();
    char* Asrc = (kt < 4) ? Alo : Ahi;
    int ko = (kt & 3) * 128;
    bf16x8 a[2][2], bb[4][2];
#pragma unroll
    for (int m = 0; m < 2; ++m)
#pragma unroll
      for (int kk = 0; kk < 2; ++kk) {
        int row = wm * 32 + m * 16 + (lane & 15);
        int off = (row * 512 + ko + kk * 64 + (lane >> 4) * 16) ^
                  ((row & 7) << 4);
        a[m][kk] = *(const bf16x8*)(Asrc + off);
      }
#pragma unroll
    for (int n = 0; n < 4; ++n)
#pragma unroll
      for (int kk = 0; kk < 2; ++kk) {
        int col = wn * 64 + n * 16 + (lane & 15);
        int off = (col * 128 + kk * 64 + (lane >> 4) * 16) ^ ((col & 7) << 4);
        bb[n][kk] = *(const bf16x8*)(ldsW3 + off);
      }
#pragma unroll
    for (int m = 0; m < 2; ++m)
#pragma unroll
      for (int n = 0; n < 4; ++n) {
        acc3[m][n] = __builtin_amdgcn_mfma_f32_16x16x32_bf16(a[m][0], bb[n][0],
                                                             acc3[m][n], 0, 0, 0);
        acc3[m][n] = __builtin_amdgcn_mfma_f32_16x16x32_bf16(a[m][1], bb[n][1],
                                                             acc3[m][n], 0, 0, 0);
      }
  }

  // epilogue: out f32 row-major
#pragma unroll
  for (int m = 0; m < 2; ++m)
#pragma unroll
    for (int n = 0; n < 4; ++n) {
      int col = wn * 64 + n * 16 + (lane & 15);
      float bv = bout[col];
#pragma unroll
      for (int r = 0; r < 4; ++r) {
        long row = row0 + wm * 32 + m * 16 + (lane >> 4) * 4 + r;
        out[row * 256 + col] = fmaxf(acc3[m][n][r] + bv, 0.f);
      }
    }
}

extern "C" void kernel_launch(void* const* d_in, const int* in_sizes, int n_in,
                              void* d_out, int out_size, void* d_ws,
                              size_t ws_size, hipStream_t stream) {
  const float* node = (const float*)d_in[0];   // [8,2048,256]
  const float* graph = (const float*)d_in[1];  // [8,2048,2048]
  const float* W1 = (const float*)d_in[2];
  const float* b1 = (const float*)d_in[3];
  const float* W2 = (const float*)d_in[4];
  const float* b2 = (const float*)d_in[5];
  const float* Wout = (const float*)d_in[6];   // [256,512]
  const float* bout = (const float*)d_in[7];
  float* out = (float*)d_out;

  char* p = (char*)d_ws;
  float* dinv = (float*)p;                    p += 16384 * 4;
  unsigned short* wb = (unsigned short*)p;    p += 262144 * 2;
  unsigned short* gb = (unsigned short*)p;    p += 8L * 2048 * 2048 * 2;  // 64MB
  unsigned short* nodeT = (unsigned short*)p; p += 8L * 256 * 2048 * 2;
  unsigned short* xT = (unsigned short*)p;    p += 8L * 256 * 2048 * 2;
  unsigned short* nodeB = (unsigned short*)p; p += 8L * 2048 * 256 * 2;

  // 1. dinv + scaled bf16 graph + weight conversion
  rowscale_cvt_k<<<4224, 256, 0, stream>>>(graph, dinv, gb, W1, W2, Wout, wb);
  // 2. node prep (nodeT for G1's B; nodeB for the final concat half)
  prep_node_k<<<dim3(32, 4, 8), 256, 0, stream>>>(node, dinv, nodeT, nodeB);
  // 3. MEGA1 -> xT
  mega1_k<<<256, 512, 0, stream>>>(gb, nodeT, wb, b1, dinv, xT);
  // 4. MEGA2+F3 -> out
  mega2f3_k<<<256, 512, 0, stream>>>(gb, xT, wb + 65536, b2, nodeB,
                                     wb + 131072, bout, out);
}